// Round 1
// baseline (1000.298 us; speedup 1.0000x reference)
//
#include <hip/hip_runtime.h>
#include <hip/hip_bf16.h>
#include <cstdint>

#define RINGN 256
#define DD    128
#define SDN   42
#define G3N   126
#define INN   64
#define BN    512
#define TN    512
#define NCN   1000

__device__ __forceinline__ float sigm(float x)    { return 1.0f / (1.0f + __expf(-x)); }
__device__ __forceinline__ float tanhfast(float x){ float e = __expf(2.0f * x); return 1.0f - 2.0f / (e + 1.0f); }
__device__ __forceinline__ float wrap256(float x) { return x - 256.0f * floorf(x * 0.00390625f); }

// Gaussian soft window around fractional ring pointer (5 taps, tau=8)
__device__ __forceinline__ void taps(float p, int* pos, float* w) {
  float base = floorf(p);
  float frac = p - base;
  int ib = (int)base;
  float e[5];
  float s = 0.0f;
#pragma unroll
  for (int k = 0; k < 5; k++) {
    float d = (float)(k - 2) - frac;
    e[k] = __expf(-(d * d) * 0.125f);
    s += e[k];
    pos[k] = (ib + k - 2) & 255;
  }
  float inv = 1.0f / s;
#pragma unroll
  for (int k = 0; k < 5; k++) w[k] = e[k] * inv;
}

// ---------------- prep: Wc = W_ih @ W_proj  [126][64], bc = b_ih + W_ih @ b_proj ----------------
__global__ void prep_kernel(const float* __restrict__ w_ih, const float* __restrict__ w_proj,
                            const float* __restrict__ b_proj, const float* __restrict__ b_ih,
                            float* __restrict__ Wc, float* __restrict__ bc) {
  int idx = blockIdx.x * 256 + threadIdx.x;
  if (idx < G3N * INN) {
    int j = idx / INN, i = idx % INN;
    float a = 0.0f;
    for (int k = 0; k < SDN; k++) a += w_ih[j * SDN + k] * w_proj[k * INN + i];
    Wc[idx] = a;
  }
  if (idx < G3N) {
    float a = b_ih[idx];
    for (int k = 0; k < SDN; k++) a += w_ih[idx * SDN + k] * b_proj[k];
    bc[idx] = a;
  }
}

// ---------------- gx GEMM: gx[B*T][126] = X[B*T][64] @ Wc.T + bc ----------------
__global__ __launch_bounds__(256)
void gx_gemm(const float* __restrict__ x, const float* __restrict__ Wc,
             const float* __restrict__ bc, float* __restrict__ gx) {
  const size_t row = (size_t)blockIdx.x * 256 + threadIdx.x;  // 262144 rows exactly
  float xr[INN];
#pragma unroll
  for (int i4 = 0; i4 < INN / 4; i4++) {
    float4 v = *reinterpret_cast<const float4*>(&x[row * INN + i4 * 4]);
    xr[i4 * 4 + 0] = v.x; xr[i4 * 4 + 1] = v.y; xr[i4 * 4 + 2] = v.z; xr[i4 * 4 + 3] = v.w;
  }
  for (int c = 0; c < G3N; c++) {
    float acc = bc[c];
    const float* wrow = &Wc[c * INN];
#pragma unroll
    for (int i4 = 0; i4 < INN / 4; i4++) {
      float4 wv = *reinterpret_cast<const float4*>(&wrow[i4 * 4]);
      acc += wv.x * xr[i4 * 4 + 0] + wv.y * xr[i4 * 4 + 1] + wv.z * xr[i4 * 4 + 2] + wv.w * xr[i4 * 4 + 3];
    }
    gx[row * G3N + c] = acc;
  }
}

// ---------------- recurrence: one wave per batch element ----------------
__global__ __launch_bounds__(64, 1)
void rec_kernel(const float* __restrict__ gx,       // [B][T][126]
                const float* __restrict__ w_hh,     // [126][42]
                const float* __restrict__ b_hh,     // [126]
                const float* __restrict__ w_bridge, // [128][42]
                const float* __restrict__ b_bridge, // [128]
                const float* __restrict__ w_jump,   // [128]
                const float* __restrict__ b_jump,   // [1]
                const float* __restrict__ w_gate,   // [128]
                const float* __restrict__ b_gate,   // [1]
                const float* __restrict__ theta,    // [1]
                float* __restrict__ ring,           // [B][256][128]
                float* __restrict__ finalptr) {     // [B]
  const int b = blockIdx.x;
  const int lane = threadIdx.x;
  const int r1 = lane + 64;

  __shared__ float Jld[RINGN];
  __shared__ float Gld[RINGN];
  __shared__ __align__(16) float h_buf[44];
  __shared__ float gh_buf[128];

  for (int i = lane; i < RINGN; i += 64) { Jld[i] = 0.0f; Gld[i] = 0.0f; }
  if (lane < 44) h_buf[lane] = 0.0f;

  // per-lane register-resident weight rows
  float Whh0[SDN], Whh1[SDN], Wb0[SDN], Wb1[SDN];
#pragma unroll
  for (int k = 0; k < SDN; k++) {
    Whh0[k] = w_hh[lane * SDN + k];
    Whh1[k] = (r1 < G3N) ? w_hh[r1 * SDN + k] : 0.0f;
    Wb0[k]  = w_bridge[lane * SDN + k];
    Wb1[k]  = w_bridge[r1 * SDN + k];
  }
  float bh0 = b_hh[lane];
  float bh1 = (r1 < G3N) ? b_hh[r1] : 0.0f;
  float bb0 = b_bridge[lane], bb1 = b_bridge[r1];
  float wj0 = w_jump[lane], wj1 = w_jump[r1];
  float wg0 = w_gate[lane], wg1 = w_gate[r1];
  float bj = b_jump[0], bg = b_gate[0];

  float hv[44];
#pragma unroll
  for (int k = 0; k < 44; k++) hv[k] = 0.0f;
  float hprev = 0.0f;

  float ptr = wrap256(theta[0]);

  const float* gxb = gx + (size_t)b * TN * G3N;
  float* ringb = ring + (size_t)b * RINGN * DD;

  float pgx0 = 0.0f, pgx1 = 0.0f, pgx2 = 0.0f;
  if (lane < SDN) {
    pgx0 = gxb[lane];
    pgx1 = gxb[SDN + lane];
    pgx2 = gxb[2 * SDN + lane];
  }

  __syncthreads();

  for (int t = 0; t < TN; t++) {
    // ---- pointer chain (replicated scalar math across lanes; independent of h chain) ----
    int pos[5]; float w[5];
    taps(ptr, pos, w);
    float Jv = 0.0f, Gv = 0.0f;
#pragma unroll
    for (int k = 0; k < 5; k++) { Jv += w[k] * Jld[pos[k]]; Gv += w[k] * Gld[pos[k]]; }
    float jump = 256.0f * sigm(Jv + bj);
    float gate = sigm(Gv + bg);
    float x0 = jump - ptr + 128.0f;
    float delta = wrap256(x0) - 128.0f;
    float ptr2 = wrap256(ptr + gate * delta);
    int pos2[5]; float w2[5];
    taps(ptr2, pos2, w2);

    // ---- h chain: gh = W_hh @ h + b_hh ----
    float gh0 = bh0, gh1 = bh1;
#pragma unroll
    for (int k = 0; k < SDN; k++) { gh0 += Whh0[k] * hv[k]; gh1 += Whh1[k] * hv[k]; }
    gh_buf[lane] = gh0;
    gh_buf[64 + lane] = gh1;
    __syncthreads();

    // ---- gates (lanes 0..41), h' write ----
    if (lane < SDN) {
      float ghr = gh_buf[lane];
      float ghz = gh_buf[SDN + lane];
      float ghn = gh_buf[2 * SDN + lane];
      float rg = sigm(pgx0 + ghr);
      float zg = sigm(pgx1 + ghz);
      float ng = tanhfast(pgx2 + rg * ghn);
      float hn = (1.0f - zg) * ng + zg * hprev;
      hprev = hn;
      h_buf[lane] = hn;
    }
    __syncthreads();

    // ---- broadcast h' to all lanes (float4 LDS reads) ----
#pragma unroll
    for (int k4 = 0; k4 < 11; k4++) {
      float4 v = *reinterpret_cast<const float4*>(&h_buf[k4 * 4]);
      hv[k4 * 4 + 0] = v.x; hv[k4 * 4 + 1] = v.y; hv[k4 * 4 + 2] = v.z; hv[k4 * 4 + 3] = v.w;
    }

    // ---- prefetch gx for t+1 ----
    if (t + 1 < TN && lane < SDN) {
      const float* g2 = gxb + (size_t)(t + 1) * G3N;
      pgx0 = g2[lane]; pgx1 = g2[SDN + lane]; pgx2 = g2[2 * SDN + lane];
    }

    // ---- u = tanh(W_bridge @ h' + b), projections ----
    float a0 = bb0, a1 = bb1;
#pragma unroll
    for (int k = 0; k < SDN; k++) { a0 += Wb0[k] * hv[k]; a1 += Wb1[k] * hv[k]; }
    float u0 = tanhfast(a0), u1 = tanhfast(a1);
    float pj = u0 * wj0 + u1 * wj1;
    float pg = u0 * wg0 + u1 * wg1;
#pragma unroll
    for (int m = 32; m >= 1; m >>= 1) {
      pj += __shfl_xor(pj, m, 64);
      pg += __shfl_xor(pg, m, 64);
    }

    // ---- ring writes: fire-and-forget atomics (only final readout consumes them) ----
#pragma unroll
    for (int k = 0; k < 5; k++) {
      atomicAdd(&ringb[pos2[k] * DD + lane], w2[k] * u0);
      atomicAdd(&ringb[pos2[k] * DD + 64 + lane], w2[k] * u1);
    }

    // ---- J/G incremental update (lanes 0..4, static-index selection via cndmask) ----
    int myp2 = pos2[0]; float myw2 = w2[0];
#pragma unroll
    for (int k = 1; k < 5; k++) {
      if (lane == k) { myp2 = pos2[k]; myw2 = w2[k]; }
    }
    if (lane < 5) {
      Jld[myp2] += myw2 * pj;
      Gld[myp2] += myw2 * pg;
    }

    ptr = ptr2;
    __syncthreads();
  }

  if (lane == 0) finalptr[b] = ptr;
}

// ---------------- final readout: r = soft-read(ring, ptr); out = r @ w_cls.T + b_cls ----------------
__global__ __launch_bounds__(256)
void readout_kernel(const float* __restrict__ ring, const float* __restrict__ finalptr,
                    const float* __restrict__ w_cls, const float* __restrict__ b_cls,
                    float* __restrict__ out) {
  const int b = blockIdx.x;
  const int tid = threadIdx.x;
  __shared__ __align__(16) float r[DD];

  float ptr = finalptr[b];
  int pos[5]; float w[5];
  taps(ptr, pos, w);
  if (tid < DD) {
    const float* rb = ring + (size_t)b * RINGN * DD;
    float acc = 0.0f;
#pragma unroll
    for (int k = 0; k < 5; k++) acc += w[k] * rb[pos[k] * DD + tid];
    r[tid] = acc;
  }
  __syncthreads();

  for (int c = tid; c < NCN; c += 256) {
    float acc = b_cls[c];
    const float* wrow = &w_cls[(size_t)c * DD];
#pragma unroll
    for (int d4 = 0; d4 < DD / 4; d4++) {
      float4 wv = *reinterpret_cast<const float4*>(&wrow[d4 * 4]);
      float4 rv = *reinterpret_cast<const float4*>(&r[d4 * 4]);
      acc += wv.x * rv.x + wv.y * rv.y + wv.z * rv.z + wv.w * rv.w;
    }
    out[(size_t)b * NCN + c] = acc;
  }
}

extern "C" void kernel_launch(void* const* d_in, const int* in_sizes, int n_in,
                              void* d_out, int out_size, void* d_ws, size_t ws_size,
                              hipStream_t stream) {
  const float* x        = (const float*)d_in[0];
  const float* theta    = (const float*)d_in[1];
  const float* w_proj   = (const float*)d_in[2];
  const float* b_proj   = (const float*)d_in[3];
  const float* w_ih     = (const float*)d_in[4];
  const float* w_hh     = (const float*)d_in[5];
  const float* b_ih     = (const float*)d_in[6];
  const float* b_hh     = (const float*)d_in[7];
  const float* w_bridge = (const float*)d_in[8];
  const float* b_bridge = (const float*)d_in[9];
  const float* w_jump   = (const float*)d_in[10];
  const float* b_jump   = (const float*)d_in[11];
  const float* w_gate   = (const float*)d_in[12];
  const float* b_gate   = (const float*)d_in[13];
  const float* w_cls    = (const float*)d_in[14];
  const float* b_cls    = (const float*)d_in[15];
  float* out = (float*)d_out;

  char* ws = (char*)d_ws;
  size_t off = 0;
  float* ring = (float*)(ws + off); off += (size_t)BN * RINGN * DD * 4;   // 64 MB
  float* gx   = (float*)(ws + off); off += (size_t)BN * TN * G3N * 4;     // 126 MB
  float* Wc   = (float*)(ws + off); off += (((size_t)G3N * INN * 4 + 255) & ~(size_t)255);
  float* bc   = (float*)(ws + off); off += 512;
  float* fptr = (float*)(ws + off); off += (size_t)BN * 4;

  hipMemsetAsync(ring, 0, (size_t)BN * RINGN * DD * 4, stream);
  prep_kernel<<<32, 256, 0, stream>>>(w_ih, w_proj, b_proj, b_ih, Wc, bc);
  gx_gemm<<<(BN * TN) / 256, 256, 0, stream>>>(x, Wc, bc, gx);
  rec_kernel<<<BN, 64, 0, stream>>>(gx, w_hh, b_hh, w_bridge, b_bridge,
                                    w_jump, b_jump, w_gate, b_gate, theta, ring, fptr);
  readout_kernel<<<BN, 256, 0, stream>>>(ring, fptr, w_cls, b_cls, out);
}